// Round 8
// baseline (328.647 us; speedup 1.0000x reference)
//
#include <hip/hip_runtime.h>
#include <stdint.h>

typedef __attribute__((ext_vector_type(4))) float f32x4;
typedef __attribute__((ext_vector_type(8))) __bf16 bf16x8;
typedef __attribute__((ext_vector_type(2))) unsigned int u32x2;

__device__ __forceinline__ uint16_t f2bf(float f) {
  uint32_t u = __builtin_bit_cast(uint32_t, f);
  u += 0x7FFFu + ((u >> 16) & 1u);
  return (uint16_t)(u >> 16);
}

__device__ __forceinline__ float bf2f(uint16_t u) {
  uint32_t v = ((uint32_t)u) << 16;
  return __builtin_bit_cast(float, v);
}

__device__ __forceinline__ uint32_t cvtpk_bf16(float lo, float hi) {
  uint32_t r;
  asm("v_cvt_pk_bf16_f32 %0, %1, %2" : "=v"(r) : "v"(lo), "v"(hi));
  return r;
}

// swap halves: a[32:63] <-> b[0:31]
__device__ __forceinline__ void swap_half32(uint32_t& a, uint32_t& b) {
#if __has_builtin(__builtin_amdgcn_permlane32_swap)
  u32x2 r = __builtin_amdgcn_permlane32_swap(a, b, false, false);
  a = r[0]; b = r[1];
#else
  int lane = __builtin_amdgcn_mbcnt_hi(~0u, __builtin_amdgcn_mbcnt_lo(~0u, 0));
  uint32_t ax = (uint32_t)__shfl_xor((int)a, 32, 64);
  uint32_t bx = (uint32_t)__shfl_xor((int)b, 32, 64);
  uint32_t an = (lane < 32) ? a : bx;
  uint32_t bn = (lane < 32) ? ax : b;
  a = an; b = bn;
#endif
}

// swap 16-lane rows: a[16:31]<->b[0:15], a[48:63]<->b[32:47]
__device__ __forceinline__ void swap_half16(uint32_t& a, uint32_t& b) {
#if __has_builtin(__builtin_amdgcn_permlane16_swap)
  u32x2 r = __builtin_amdgcn_permlane16_swap(a, b, false, false);
  a = r[0]; b = r[1];
#else
  int lane = __builtin_amdgcn_mbcnt_hi(~0u, __builtin_amdgcn_mbcnt_lo(~0u, 0));
  uint32_t ax = (uint32_t)__shfl_xor((int)a, 16, 64);
  uint32_t bx = (uint32_t)__shfl_xor((int)b, 16, 64);
  uint32_t an = ((lane & 16) == 0) ? a : bx;
  uint32_t bn = ((lane & 16) == 0) ? ax : b;
  a = an; b = bn;
#endif
}

__device__ __forceinline__ void load_lds16(const uint16_t* g, uint16_t* l) {
  __builtin_amdgcn_global_load_lds((const __attribute__((address_space(1))) void*)g,
                                   (__attribute__((address_space(3))) void*)l, 16, 0, 0);
}

// ---------------- fused prep: convert x+ctx to bf16, transpose 3 W's ----------------
// R14: also zeroes the 128 merge counters (block 0).
__global__ __launch_bounds__(256) void k_prep(const float* __restrict__ x,
                                              const float* __restrict__ ctx,
                                              const float* __restrict__ Wq,
                                              const float* __restrict__ Wkv,
                                              const float* __restrict__ Wout,
                                              uint16_t* __restrict__ xb,
                                              uint16_t* __restrict__ ctxb,
                                              uint16_t* __restrict__ wqt,
                                              uint16_t* __restrict__ wkvt,
                                              uint16_t* __restrict__ woutt,
                                              int* __restrict__ ctr,
                                              float qscale) {
  __shared__ float tile[32][33];
  int id = blockIdx.x;
  int tid = threadIdx.x;
  if (id == 0 && tid < 128) ctr[tid] = 0;
  if (id < 10240) {
    const float* in;
    uint16_t* out;
    int j = id * 256 + tid;
    if (j < 524288) { in = x; out = xb; }
    else            { in = ctx; out = ctxb; j -= 524288; }
    float4 v = ((const float4*)in)[j];
    union { uint16_t u[4]; uint64_t q; } o;
    o.u[0] = f2bf(v.x); o.u[1] = f2bf(v.y); o.u[2] = f2bf(v.z); o.u[3] = f2bf(v.w);
    ((uint64_t*)out)[j] = o.q;
    return;
  }
  id -= 10240;
  const float* W;
  uint16_t* Wt;
  int N, n0, k0;
  float sc = 1.0f;
  if (id < 1024)      { W = Wq;   Wt = wqt;   N = 1024; sc = qscale;
                        n0 = (id & 31) * 32; k0 = (id >> 5) * 32; }
  else if (id < 2048) { W = Wout; Wt = woutt; N = 1024; id -= 1024;
                        n0 = (id & 31) * 32; k0 = (id >> 5) * 32; }
  else                { W = Wkv;  Wt = wkvt;  N = 2048; id -= 2048;
                        n0 = (id & 63) * 32; k0 = (id >> 6) * 32; }
  int c = tid & 31, r0 = tid >> 5;
#pragma unroll
  for (int i = 0; i < 4; i++) {
    int r = r0 + i * 8;
    tile[r][c] = W[(size_t)(k0 + r) * N + n0 + c];
  }
  __syncthreads();
#pragma unroll
  for (int i = 0; i < 4; i++) {
    int r = r0 + i * 8;
    Wt[(size_t)(n0 + r) * 1024 + k0 + c] = f2bf(tile[c][r] * sc);
  }
}

// ---------------- fused GEMM: kv = ctx @ Wkv (K->kb head-major, V->vtb^T) and q = x @ Wq' ----------------
// R10b structure (proven fastest): 2-slot double-buffered LDS + counted vmcnt(4).
__global__ __launch_bounds__(256, 4) void k_gemm_fused(const uint16_t* __restrict__ ctxb,
                                                       const uint16_t* __restrict__ wkvt,
                                                       const uint16_t* __restrict__ xb,
                                                       const uint16_t* __restrict__ wqt,
                                                       uint16_t* __restrict__ kb,
                                                       uint16_t* __restrict__ vtb,
                                                       uint16_t* __restrict__ qb) {
  __shared__ uint16_t smem[16384]; // 2 slots x (A 4096 + B 4096); V-epilogue reuses [0,9216)
  const int K = 1024;
  const int tid = threadIdx.x;
  const int lane = tid & 63, w = tid >> 6;
  const int quad = lane >> 4, l16 = lane & 15;
  const int wr = (w >> 1) * 64, wc = (w & 1) * 64;
  int id = blockIdx.x;
  int bx, by, isQ;
  const uint16_t *Ab, *Bb;
  if (id < 1024) {
    isQ = 0;
    int xcd = id & 7, t = id >> 3;         // t in [0,128)
    by = (xcd << 3) + (t & 7);             // 8 A-panels per XCD
    bx = t >> 3;                           // all 16 col tiles co-XCD
    Ab = ctxb + (size_t)by * 128 * K;
    Bb = wkvt + (size_t)bx * 128 * K;
  } else {
    isQ = 1; id -= 1024;
    int xcd = id & 7, t = id >> 3;         // t in [0,16)
    by = (xcd << 1) + (t & 1);             // 2 A-panels per XCD
    bx = t >> 1;
    Ab = xb + (size_t)by * 128 * K;
    Bb = wqt + (size_t)bx * 128 * K;
  }
  f32x4 acc[4][4] = {};
  const int rA = tid >> 2, slotA = tid & 3;
  const int rA1 = rA + 64;
  const int segA0 = (slotA ^ ((rA + (rA >> 2)) & 3)) * 8;
  const int segA1 = (slotA ^ ((rA1 + (rA1 >> 2)) & 3)) * 8;
  const uint16_t* gA0 = Ab + (size_t)rA * K + segA0;
  const uint16_t* gA1 = Ab + (size_t)rA1 * K + segA1;
  const uint16_t* gB0 = Bb + (size_t)rA * K + segA0;
  const uint16_t* gB1 = Bb + (size_t)rA1 * K + segA1;
  // prologue: stage tile 0 into slot 0
  load_lds16(gA0, smem + tid * 8);
  load_lds16(gA1, smem + (tid + 256) * 8);
  load_lds16(gB0, smem + (tid + 512) * 8);
  load_lds16(gB1, smem + (tid + 768) * 8);
  for (int t = 0; t < 32; ++t) {
    const uint16_t* la = smem + (t & 1) * 8192;
    const uint16_t* lb = la + 4096;
    if (t < 31) {
      uint16_t* ln = smem + ((t + 1) & 1) * 8192;
      const int k1 = (t + 1) * 32;
      load_lds16(gA0 + k1, ln + tid * 8);
      load_lds16(gA1 + k1, ln + (tid + 256) * 8);
      load_lds16(gB0 + k1, ln + (tid + 512) * 8);
      load_lds16(gB1 + k1, ln + (tid + 768) * 8);
      asm volatile("s_waitcnt vmcnt(4)\n\ts_barrier" ::: "memory");
    } else {
      asm volatile("s_waitcnt vmcnt(0)\n\ts_barrier" ::: "memory");
    }
    bf16x8 af[4], bfr[4];
#pragma unroll
    for (int i = 0; i < 4; i++) {
      int R = wr + i * 16 + l16;
      int s = quad ^ ((R + (R >> 2)) & 3);
      af[i] = *(const bf16x8*)&la[R * 32 + s * 8];
    }
#pragma unroll
    for (int j = 0; j < 4; j++) {
      int R = wc + j * 16 + l16;
      int s = quad ^ ((R + (R >> 2)) & 3);
      bfr[j] = *(const bf16x8*)&lb[R * 32 + s * 8];
    }
    __builtin_amdgcn_s_setprio(1);
#pragma unroll
    for (int i = 0; i < 4; i++)
#pragma unroll
      for (int j = 0; j < 4; j++)
        acc[i][j] = __builtin_amdgcn_mfma_f32_16x16x32_bf16(af[i], bfr[j], acc[i][j], 0, 0, 0);
    __builtin_amdgcn_s_setprio(0);
    asm volatile("s_barrier" ::: "memory");
  }
  __syncthreads();
  if (isQ) {
#pragma unroll
    for (int i = 0; i < 4; i++)
#pragma unroll
      for (int j = 0; j < 4; j++) {
        size_t row = (size_t)by * 128 + wr + i * 16 + quad * 4;
        size_t col = (size_t)bx * 128 + wc + j * 16 + l16;
#pragma unroll
        for (int r = 0; r < 4; r++)
          qb[(row + r) * 1024 + col] = f2bf(acc[i][j][r]);
      }
  } else if (bx < 8) {
    // K region: head-major kb[b][h=bx][l][128]
#pragma unroll
    for (int i = 0; i < 4; i++)
#pragma unroll
      for (int j = 0; j < 4; j++) {
        int rowg = by * 128 + wr + i * 16 + quad * 4; // global ctx row
        int bb = rowg >> 12, l = rowg & 4095;
        int c = wc + j * 16 + l16;
        uint16_t* dst = kb + (((size_t)(bb * 8 + bx) * 4096 + l) * 128 + c);
#pragma unroll
        for (int r = 0; r < 4; r++)
          dst[r * 128] = f2bf(acc[i][j][r]);
      }
  } else {
    // V region: tile = head (bx-8); bounce col-major through LDS, wide stores
    const int bh = (by >> 5) * 8 + (bx - 8);
    const int lbase = (by & 31) * 128;
    uint16_t* vdst = vtb + (size_t)bh * 524288;
#pragma unroll
    for (int half = 0; half < 2; half++) {
      if (wr == half * 64) {
#pragma unroll
        for (int i = 0; i < 4; i++)
#pragma unroll
          for (int j = 0; j < 4; j++) {
            int rowl = i * 16 + quad * 4;
            int col = wc + j * 16 + l16;
            union { uint64_t q; uint16_t u[4]; } pk;
#pragma unroll
            for (int r = 0; r < 4; r++) pk.u[r] = f2bf(acc[i][j][r]);
            *(uint64_t*)&smem[col * 72 + rowl] = pk.q;
          }
      }
      __syncthreads();
      {
        int col = tid >> 1, rseg = (tid & 1) * 32;
        const uint16_t* src = &smem[col * 72 + rseg];
        uint16_t* d = vdst + (size_t)col * 4096 + lbase + half * 64 + rseg;
#pragma unroll
        for (int k = 0; k < 4; k++)
          ((uint4*)d)[k] = *(const uint4*)&src[k * 8];
      }
      __syncthreads();
    }
  }
}

// ---------------- GEMM 64x64 tile, BK=64 (for out), dbuf + counted vmcnt ----------------
__global__ __launch_bounds__(256) void k_gemm64(const uint16_t* __restrict__ A,
                                                const uint16_t* __restrict__ Bt,
                                                float* __restrict__ Cf,
                                                const float* __restrict__ bias,
                                                int M, int N, int K) {
  __shared__ uint16_t smem[16384]; // 2 slots x (A 4096 + B 4096)
  const int tid = threadIdx.x;
  const int lane = tid & 63, w = tid >> 6;
  const int quad = lane >> 4, l16 = lane & 15;
  const int wr = (w >> 1) * 32, wc = (w & 1) * 32;
  const size_t tr0 = (size_t)blockIdx.y * 64, tc0 = (size_t)blockIdx.x * 64;
  f32x4 acc[2][2] = {};
  const int rS = tid >> 3, sS = tid & 7;
  const int seg = (sS ^ (rS & 7)) * 8;
  const uint16_t* Ab = A + tr0 * K;
  const uint16_t* Bb = Bt + tc0 * K;
  const uint16_t* gA0 = Ab + (size_t)rS * K + seg;
  const uint16_t* gA1 = Ab + (size_t)(rS + 32) * K + seg;
  const uint16_t* gB0 = Bb + (size_t)rS * K + seg;
  const uint16_t* gB1 = Bb + (size_t)(rS + 32) * K + seg;
  const int NT = K >> 6;
  load_lds16(gA0, smem + tid * 8);
  load_lds16(gA1, smem + (tid + 256) * 8);
  load_lds16(gB0, smem + (tid + 512) * 8);
  load_lds16(gB1, smem + (tid + 768) * 8);
  for (int t = 0; t < NT; ++t) {
    const uint16_t* la = smem + (t & 1) * 8192;
    const uint16_t* lb = la + 4096;
    if (t < NT - 1) {
      uint16_t* ln = smem + ((t + 1) & 1) * 8192;
      const int k1 = (t + 1) * 64;
      load_lds16(gA0 + k1, ln + tid * 8);
      load_lds16(gA1 + k1, ln + (tid + 256) * 8);
      load_lds16(gB0 + k1, ln + (tid + 512) * 8);
      load_lds16(gB1 + k1, ln + (tid + 768) * 8);
      asm volatile("s_waitcnt vmcnt(4)\n\ts_barrier" ::: "memory");
    } else {
      asm volatile("s_waitcnt vmcnt(0)\n\ts_barrier" ::: "memory");
    }
    __builtin_amdgcn_s_setprio(1);
#pragma unroll
    for (int sub = 0; sub < 2; sub++) {
      const int kk = sub * 4 + quad;
      bf16x8 af[2], bfr[2];
#pragma unroll
      for (int i = 0; i < 2; i++) {
        int R = wr + i * 16 + l16;
        af[i] = *(const bf16x8*)&la[R * 64 + (kk ^ (R & 7)) * 8];
      }
#pragma unroll
      for (int j = 0; j < 2; j++) {
        int R = wc + j * 16 + l16;
        bfr[j] = *(const bf16x8*)&lb[R * 64 + (kk ^ (R & 7)) * 8];
      }
#pragma unroll
      for (int i = 0; i < 2; i++)
#pragma unroll
        for (int j = 0; j < 2; j++)
          acc[i][j] = __builtin_amdgcn_mfma_f32_16x16x32_bf16(af[i], bfr[j], acc[i][j], 0, 0, 0);
    }
    __builtin_amdgcn_s_setprio(0);
    asm volatile("s_barrier" ::: "memory");
  }
#pragma unroll
  for (int i = 0; i < 2; i++) {
#pragma unroll
    for (int j = 0; j < 2; j++) {
      size_t row = tr0 + wr + i * 16 + quad * 4;
      size_t col = tc0 + wc + j * 16 + l16;
#pragma unroll
      for (int r = 0; r < 4; r++)
        Cf[(row + r) * N + col] = acc[i][j][r] + bias[col];
    }
  }
}

// ---------------- flash attention, key-split x4 + fused last-block merge ----------------
// R14: the 4 sp-blocks sharing (qbx,h,b) coordinate via a device-scope counter;
// the last one merges its 128qi x 128d slice (po/pl are L2/L3-hot) and writes
// attb directly. Deletes the k_merge kernel (launch + full HBM pass).
__global__ __launch_bounds__(256) void k_attn(const uint16_t* __restrict__ q,
                                              const uint16_t* __restrict__ kb,
                                              const uint16_t* __restrict__ vt,
                                              const float* __restrict__ sims,
                                              const float* __restrict__ beta,
                                              uint16_t* __restrict__ po,
                                              float* __restrict__ pl,
                                              uint16_t* __restrict__ attb,
                                              int* __restrict__ ctr) {
  __shared__ uint16_t Kl[2][8192]; // 64 keys x 128 hd, seg-swizzled (2x16 KB)
  __shared__ uint16_t Vl[2][8192]; // 128 d x 64 keys, seg-swizzled (2x16 KB)
  __shared__ int last_flag;
  const int idx = blockIdx.x;
  const int qbx = idx >> 6, g = idx & 63;
  const int h = g >> 3, b = (g >> 2) & 1, sp = g & 3;
  const int q0 = qbx * 128;
  const int tid = threadIdx.x, lane = tid & 63, w = tid >> 6;
  const int quad = lane >> 4, l16 = lane & 15;
  const float wsplit =
      __builtin_amdgcn_exp2f(sims[b * 4 + sp] * beta[0] * 1.44269504f);

  union { uint32_t u[4]; bf16x8 v; } Oc;
#pragma unroll
  for (int j = 0; j < 4; j++) Oc.u[j] = 0x3F803F80u;
  const bf16x8 onesf = Oc.v;

  bf16x8 qf[2][4];
#pragma unroll
  for (int rb = 0; rb < 2; rb++) {
    const uint16_t* qrow =
        q + ((size_t)(b * 1024 + q0 + w * 32 + rb * 16 + l16)) * 1024 + h * 128 + quad * 8;
#pragma unroll
    for (int ks = 0; ks < 4; ks++) qf[rb][ks] = *(const bf16x8*)(qrow + ks * 32);
  }
  f32x4 o[2][8] = {};
  f32x4 o9[2] = {};

  const uint16_t* kptr = kb + ((size_t)(b * 8 + h) * 4096 + sp * 1024) * 128;
  const uint16_t* vptr = vt + ((size_t)(b * 8 + h) * 128) * 4096 + sp * 1024;

  // prologue: stage chunk 0 into slot 0
#pragma unroll
  for (int ii = 0; ii < 4; ii++) {
    int g2 = tid + ii * 256;
    int row = g2 >> 4, seg = (g2 & 15) ^ (row & 15);
    load_lds16(kptr + row * 128 + seg * 8, &Kl[0][g2 * 8]);
  }
#pragma unroll
  for (int ii = 0; ii < 4; ii++) {
    int g2 = tid + ii * 256;
    int row = g2 >> 3, seg = (g2 & 7) ^ (row & 7);
    load_lds16(vptr + (size_t)row * 4096 + seg * 8, &Vl[0][g2 * 8]);
  }

  for (int c = 0; c < 16; c++) {
    const uint16_t* Kc = Kl[c & 1];
    const uint16_t* Vc = Vl[c & 1];
    if (c < 15) {
      const uint16_t* kn = kptr + 64 * 128;
      const uint16_t* vn = vptr + 64;
      uint16_t* Kd = Kl[(c + 1) & 1];
      uint16_t* Vd = Vl[(c + 1) & 1];
#pragma unroll
      for (int ii = 0; ii < 4; ii++) {
        int g2 = tid + ii * 256;
        int row = g2 >> 4, seg = (g2 & 15) ^ (row & 15);
        load_lds16(kn + row * 128 + seg * 8, Kd + g2 * 8);
      }
#pragma unroll
      for (int ii = 0; ii < 4; ii++) {
        int g2 = tid + ii * 256;
        int row = g2 >> 3, seg = (g2 & 7) ^ (row & 7);
        load_lds16(vn + (size_t)row * 4096 + seg * 8, Vd + g2 * 8);
      }
      asm volatile("s_waitcnt vmcnt(8)\n\ts_barrier" ::: "memory");
    } else {
      asm volatile("s_waitcnt vmcnt(0)\n\ts_barrier" ::: "memory");
    }
#pragma unroll
    for (int kh = 0; kh < 2; kh++) {
      // swapped QK: C col=l16=q, row=quad*4+r=key (key = nb*16 + quad*4 + r)
      f32x4 s[2][2] = {{{0.f,0.f,0.f,0.f},{0.f,0.f,0.f,0.f}},
                       {{0.f,0.f,0.f,0.f},{0.f,0.f,0.f,0.f}}};
      __builtin_amdgcn_s_setprio(1);
#pragma unroll
      for (int nb2 = 0; nb2 < 2; nb2++) {
        const int nb = kh * 2 + nb2;
#pragma unroll
        for (int ks = 0; ks < 4; ks++) {
          bf16x8 kf = *(const bf16x8*)&Kc[(nb * 16 + l16) * 128 + (((ks * 4 + quad) ^ l16) * 8)];
          s[nb2][0] = __builtin_amdgcn_mfma_f32_16x16x32_bf16(kf, qf[0][ks], s[nb2][0], 0, 0, 0);
          s[nb2][1] = __builtin_amdgcn_mfma_f32_16x16x32_bf16(kf, qf[1][ks], s[nb2][1], 0, 0, 0);
        }
      }
      __builtin_amdgcn_s_setprio(0);
      // exp2 + pack + cross-quad redistribution -> PV A-frags, all in registers.
      bf16x8 pa[2];
#pragma unroll
      for (int qh = 0; qh < 2; qh++) {
        uint32_t a0 = cvtpk_bf16(__builtin_amdgcn_exp2f(s[0][qh][0]),
                                 __builtin_amdgcn_exp2f(s[0][qh][1]));
        uint32_t a1 = cvtpk_bf16(__builtin_amdgcn_exp2f(s[0][qh][2]),
                                 __builtin_amdgcn_exp2f(s[0][qh][3]));
        uint32_t b0 = cvtpk_bf16(__builtin_amdgcn_exp2f(s[1][qh][0]),
                                 __builtin_amdgcn_exp2f(s[1][qh][1]));
        uint32_t b1 = cvtpk_bf16(__builtin_amdgcn_exp2f(s[1][qh][2]),
                                 __builtin_amdgcn_exp2f(s[1][qh][3]));
        swap_half32(a0, b0);
        swap_half16(a0, b0);
        swap_half32(a1, b1);
        swap_half16(a1, b1);
        union { uint32_t u[4]; bf16x8 v; } pk_;
        pk_.u[0] = a0; pk_.u[1] = a1; pk_.u[2] = b0; pk_.u[3] = b1;
        pa[qh] = pk_.v;
      }
      // PV for this half
      const int sq = ((kh * 4 + quad) ^ (l16 & 7)) * 8;
      __builtin_amdgcn_s_setprio(1);
#pragma unroll
      for (int nb = 0; nb < 8; nb++) {
        bf16x8 vf = *(const bf16x8*)&Vc[(nb * 16 + l16) * 64 + sq];
        o[0][nb] = __builtin_amdgcn_mfma_f32_16x16x32_bf16(pa[0], vf, o[0][nb], 0, 0, 0);
        o[1][nb] = __builtin_amdgcn_mfma_f32_16x16x32_bf16(pa[1], vf, o[1][nb], 0, 0, 0);
      }
      o9[0] = __builtin_amdgcn_mfma_f32_16x16x32_bf16(pa[0], onesf, o9[0], 0, 0, 0);
      o9[1] = __builtin_amdgcn_mfma_f32_16x16x32_bf16(pa[1], onesf, o9[1], 0, 0, 0);
      __builtin_amdgcn_s_setprio(0);
    }
    asm volatile("s_barrier" ::: "memory"); // WAR guard before next restage
    kptr += 64 * 128;
    vptr += 64;
  }
  // epilogue: sim-weighted partial O (bf16) + weighted row sums
  const int rowbase = (sp * 16 + b * 8 + h) * 1024 + q0 + w * 32;
#pragma unroll
  for (int rb = 0; rb < 2; rb++)
#pragma unroll
    for (int r = 0; r < 4; r++) {
      int row = rowbase + rb * 16 + quad * 4 + r;
#pragma unroll
      for (int nb = 0; nb < 8; nb++)
        po[(size_t)row * 128 + nb * 16 + l16] = f2bf(o[rb][nb][r] * wsplit);
      if (l16 == 0)
        pl[row] = o9[rb][r] * wsplit;
    }
  // ---- fused merge: last of the 4 sp-blocks for (qbx,h,b) merges its slice ----
  __threadfence();           // release this block's po/pl stores (device scope)
  __syncthreads();
  if (tid == 0)
    last_flag = (atomicAdd(&ctr[(qbx << 4) | (h << 1) | b], 1) == 3);
  __syncthreads();
  if (!last_flag) return;
  __threadfence();           // acquire the other 3 blocks' po/pl stores
  const int bh2 = b * 8 + h;
  const int qi = q0 + (tid >> 1);
  const int d0 = (tid & 1) * 64;
  float den = 0.f;
#pragma unroll
  for (int s2 = 0; s2 < 4; s2++) den += pl[((s2 * 16 + bh2) << 10) + qi];
  const float inv = 1.0f / den;
  uint16_t* dstp = attb + ((size_t)(b * 1024 + qi)) * 1024 + h * 128 + d0;
#pragma unroll
  for (int dc = 0; dc < 64; dc += 8) {
    float acc8[8] = {0.f, 0.f, 0.f, 0.f, 0.f, 0.f, 0.f, 0.f};
#pragma unroll
    for (int s2 = 0; s2 < 4; s2++) {
      const uint16_t* src = po + (((size_t)(s2 * 16 + bh2) * 1024 + qi) * 128) + d0 + dc;
      union { uint4 v; uint16_t u[8]; } ld;
      ld.v = *(const uint4*)src;
#pragma unroll
      for (int j = 0; j < 8; j++) acc8[j] += bf2f(ld.u[j]);
    }
    union { uint4 v; uint16_t u[8]; } st;
#pragma unroll
    for (int j = 0; j < 8; j++) st.u[j] = f2bf(acc8[j] * inv);
    *(uint4*)(dstp + dc) = st.v;
  }
}

// ---------------- launch ----------------
extern "C" void kernel_launch(void* const* d_in, const int* in_sizes, int n_in,
                              void* d_out, int out_size, void* d_ws, size_t ws_size,
                              hipStream_t stream) {
  (void)in_sizes; (void)n_in; (void)out_size; (void)ws_size;
  const float* x    = (const float*)d_in[0];
  const float* ctx  = (const float*)d_in[1];
  const float* sims = (const float*)d_in[2];
  const float* Wq   = (const float*)d_in[3];
  const float* Wkv  = (const float*)d_in[4];
  const float* beta = (const float*)d_in[5];
  const float* Wout = (const float*)d_in[6];
  const float* bout = (const float*)d_in[7];
  float* out = (float*)d_out;

  char* ws = (char*)d_ws;
  uint16_t* xb    = (uint16_t*)(ws + 0);           // 4 MB  (dead after fused GEMM)
  uint16_t* ctxb  = (uint16_t*)(ws + (4u << 20));  // 16 MB (dead after fused GEMM)
  uint16_t* wqt   = (uint16_t*)(ws + (20u << 20)); // 2 MB  (dead after fused GEMM)
  uint16_t* wkvt  = (uint16_t*)(ws + (22u << 20)); // 4 MB  (dead after fused GEMM)
  uint16_t* kb    = (uint16_t*)(ws + (32u << 20)); // 16 MB [2][8][4096][128]
  uint16_t* vtb   = (uint16_t*)(ws + (48u << 20)); // 16 MB [16][128][4096]
  float*    pl    = (float*)   (ws + (64u << 20)); // 256 KB used [64][1024]
  int*      ctr   = (int*)     (ws + (66u << 20)); // 512 B (128 counters)
  uint16_t* woutt = (uint16_t*)(ws + (68u << 20)); // 2 MB (live till end)
  uint16_t* qb    = (uint16_t*)(ws + (70u << 20)); // 4 MB (live till attn)
  uint16_t* attb  = (uint16_t*)(ws + (74u << 20)); // 4 MB
  // po (16 MB) reuses 0..16 MB: xb/ctxb dead by attention time
  uint16_t* po = (uint16_t*)(ws + 0);              // 16 MB [64][1024][128]

  const float LOG2E = 1.44269504f;
  const float qscale = 0.03125f * LOG2E;

  k_prep<<<14336, 256, 0, stream>>>(x, ctx, Wq, Wkv, Wout, xb, ctxb, wqt, wkvt, woutt, ctr, qscale);
  k_gemm_fused<<<1152, 256, 0, stream>>>(ctxb, wkvt, xb, wqt, kb, vtb, qb);
  k_attn<<<512, 256, 0, stream>>>(qb, kb, vtb, sims, beta, po, pl, attb, ctr);
  k_gemm64<<<dim3(16, 32), 256, 0, stream>>>(attb, woutt, out, bout, 2048, 1024, 1024);
}

// Round 9
// 221.997 us; speedup vs baseline: 1.4804x; 1.4804x over previous
//
#include <hip/hip_runtime.h>
#include <stdint.h>

typedef __attribute__((ext_vector_type(4))) float f32x4;
typedef __attribute__((ext_vector_type(8))) __bf16 bf16x8;
typedef __attribute__((ext_vector_type(2))) unsigned int u32x2;

__device__ __forceinline__ uint16_t f2bf(float f) {
  uint32_t u = __builtin_bit_cast(uint32_t, f);
  u += 0x7FFFu + ((u >> 16) & 1u);
  return (uint16_t)(u >> 16);
}

__device__ __forceinline__ float bf2f(uint16_t u) {
  uint32_t v = ((uint32_t)u) << 16;
  return __builtin_bit_cast(float, v);
}

__device__ __forceinline__ uint32_t cvtpk_bf16(float lo, float hi) {
  uint32_t r;
  asm("v_cvt_pk_bf16_f32 %0, %1, %2" : "=v"(r) : "v"(lo), "v"(hi));
  return r;
}

// swap halves: a[32:63] <-> b[0:31]
__device__ __forceinline__ void swap_half32(uint32_t& a, uint32_t& b) {
#if __has_builtin(__builtin_amdgcn_permlane32_swap)
  u32x2 r = __builtin_amdgcn_permlane32_swap(a, b, false, false);
  a = r[0]; b = r[1];
#else
  int lane = __builtin_amdgcn_mbcnt_hi(~0u, __builtin_amdgcn_mbcnt_lo(~0u, 0));
  uint32_t ax = (uint32_t)__shfl_xor((int)a, 32, 64);
  uint32_t bx = (uint32_t)__shfl_xor((int)b, 32, 64);
  uint32_t an = (lane < 32) ? a : bx;
  uint32_t bn = (lane < 32) ? ax : b;
  a = an; b = bn;
#endif
}

// swap 16-lane rows: a[16:31]<->b[0:15], a[48:63]<->b[32:47]
__device__ __forceinline__ void swap_half16(uint32_t& a, uint32_t& b) {
#if __has_builtin(__builtin_amdgcn_permlane16_swap)
  u32x2 r = __builtin_amdgcn_permlane16_swap(a, b, false, false);
  a = r[0]; b = r[1];
#else
  int lane = __builtin_amdgcn_mbcnt_hi(~0u, __builtin_amdgcn_mbcnt_lo(~0u, 0));
  uint32_t ax = (uint32_t)__shfl_xor((int)a, 16, 64);
  uint32_t bx = (uint32_t)__shfl_xor((int)b, 16, 64);
  uint32_t an = ((lane & 16) == 0) ? a : bx;
  uint32_t bn = ((lane & 16) == 0) ? ax : b;
  a = an; b = bn;
#endif
}

__device__ __forceinline__ void load_lds16(const uint16_t* g, uint16_t* l) {
  __builtin_amdgcn_global_load_lds((const __attribute__((address_space(1))) void*)g,
                                   (__attribute__((address_space(3))) void*)l, 16, 0, 0);
}

// ---------------- fused prep: convert x+ctx to bf16, transpose 3 W's ----------------
__global__ __launch_bounds__(256) void k_prep(const float* __restrict__ x,
                                              const float* __restrict__ ctx,
                                              const float* __restrict__ Wq,
                                              const float* __restrict__ Wkv,
                                              const float* __restrict__ Wout,
                                              uint16_t* __restrict__ xb,
                                              uint16_t* __restrict__ ctxb,
                                              uint16_t* __restrict__ wqt,
                                              uint16_t* __restrict__ wkvt,
                                              uint16_t* __restrict__ woutt,
                                              float qscale) {
  __shared__ float tile[32][33];
  int id = blockIdx.x;
  int tid = threadIdx.x;
  if (id < 10240) {
    const float* in;
    uint16_t* out;
    int j = id * 256 + tid;
    if (j < 524288) { in = x; out = xb; }
    else            { in = ctx; out = ctxb; j -= 524288; }
    float4 v = ((const float4*)in)[j];
    union { uint16_t u[4]; uint64_t q; } o;
    o.u[0] = f2bf(v.x); o.u[1] = f2bf(v.y); o.u[2] = f2bf(v.z); o.u[3] = f2bf(v.w);
    ((uint64_t*)out)[j] = o.q;
    return;
  }
  id -= 10240;
  const float* W;
  uint16_t* Wt;
  int N, n0, k0;
  float sc = 1.0f;
  if (id < 1024)      { W = Wq;   Wt = wqt;   N = 1024; sc = qscale;
                        n0 = (id & 31) * 32; k0 = (id >> 5) * 32; }
  else if (id < 2048) { W = Wout; Wt = woutt; N = 1024; id -= 1024;
                        n0 = (id & 31) * 32; k0 = (id >> 5) * 32; }
  else                { W = Wkv;  Wt = wkvt;  N = 2048; id -= 2048;
                        n0 = (id & 63) * 32; k0 = (id >> 6) * 32; }
  int c = tid & 31, r0 = tid >> 5;
#pragma unroll
  for (int i = 0; i < 4; i++) {
    int r = r0 + i * 8;
    tile[r][c] = W[(size_t)(k0 + r) * N + n0 + c];
  }
  __syncthreads();
#pragma unroll
  for (int i = 0; i < 4; i++) {
    int r = r0 + i * 8;
    Wt[(size_t)(n0 + r) * 1024 + k0 + c] = f2bf(tile[c][r] * sc);
  }
}

// ---------------- fused GEMM: kv = ctx @ Wkv (K->kb head-major, V->vtb^T) and q = x @ Wq' ----------------
// R10b structure (proven fastest): 2-slot double-buffered LDS + counted vmcnt(4).
__global__ __launch_bounds__(256, 4) void k_gemm_fused(const uint16_t* __restrict__ ctxb,
                                                       const uint16_t* __restrict__ wkvt,
                                                       const uint16_t* __restrict__ xb,
                                                       const uint16_t* __restrict__ wqt,
                                                       uint16_t* __restrict__ kb,
                                                       uint16_t* __restrict__ vtb,
                                                       uint16_t* __restrict__ qb) {
  __shared__ uint16_t smem[16384]; // 2 slots x (A 4096 + B 4096); V-epilogue reuses [0,9216)
  const int K = 1024;
  const int tid = threadIdx.x;
  const int lane = tid & 63, w = tid >> 6;
  const int quad = lane >> 4, l16 = lane & 15;
  const int wr = (w >> 1) * 64, wc = (w & 1) * 64;
  int id = blockIdx.x;
  int bx, by, isQ;
  const uint16_t *Ab, *Bb;
  if (id < 1024) {
    isQ = 0;
    int xcd = id & 7, t = id >> 3;         // t in [0,128)
    by = (xcd << 3) + (t & 7);             // 8 A-panels per XCD
    bx = t >> 3;                           // all 16 col tiles co-XCD
    Ab = ctxb + (size_t)by * 128 * K;
    Bb = wkvt + (size_t)bx * 128 * K;
  } else {
    isQ = 1; id -= 1024;
    int xcd = id & 7, t = id >> 3;         // t in [0,16)
    by = (xcd << 1) + (t & 1);             // 2 A-panels per XCD
    bx = t >> 1;
    Ab = xb + (size_t)by * 128 * K;
    Bb = wqt + (size_t)bx * 128 * K;
  }
  f32x4 acc[4][4] = {};
  const int rA = tid >> 2, slotA = tid & 3;
  const int rA1 = rA + 64;
  const int segA0 = (slotA ^ ((rA + (rA >> 2)) & 3)) * 8;
  const int segA1 = (slotA ^ ((rA1 + (rA1 >> 2)) & 3)) * 8;
  const uint16_t* gA0 = Ab + (size_t)rA * K + segA0;
  const uint16_t* gA1 = Ab + (size_t)rA1 * K + segA1;
  const uint16_t* gB0 = Bb + (size_t)rA * K + segA0;
  const uint16_t* gB1 = Bb + (size_t)rA1 * K + segA1;
  // prologue: stage tile 0 into slot 0
  load_lds16(gA0, smem + tid * 8);
  load_lds16(gA1, smem + (tid + 256) * 8);
  load_lds16(gB0, smem + (tid + 512) * 8);
  load_lds16(gB1, smem + (tid + 768) * 8);
  for (int t = 0; t < 32; ++t) {
    const uint16_t* la = smem + (t & 1) * 8192;
    const uint16_t* lb = la + 4096;
    if (t < 31) {
      uint16_t* ln = smem + ((t + 1) & 1) * 8192;
      const int k1 = (t + 1) * 32;
      load_lds16(gA0 + k1, ln + tid * 8);
      load_lds16(gA1 + k1, ln + (tid + 256) * 8);
      load_lds16(gB0 + k1, ln + (tid + 512) * 8);
      load_lds16(gB1 + k1, ln + (tid + 768) * 8);
      asm volatile("s_waitcnt vmcnt(4)\n\ts_barrier" ::: "memory");
    } else {
      asm volatile("s_waitcnt vmcnt(0)\n\ts_barrier" ::: "memory");
    }
    bf16x8 af[4], bfr[4];
#pragma unroll
    for (int i = 0; i < 4; i++) {
      int R = wr + i * 16 + l16;
      int s = quad ^ ((R + (R >> 2)) & 3);
      af[i] = *(const bf16x8*)&la[R * 32 + s * 8];
    }
#pragma unroll
    for (int j = 0; j < 4; j++) {
      int R = wc + j * 16 + l16;
      int s = quad ^ ((R + (R >> 2)) & 3);
      bfr[j] = *(const bf16x8*)&lb[R * 32 + s * 8];
    }
    __builtin_amdgcn_s_setprio(1);
#pragma unroll
    for (int i = 0; i < 4; i++)
#pragma unroll
      for (int j = 0; j < 4; j++)
        acc[i][j] = __builtin_amdgcn_mfma_f32_16x16x32_bf16(af[i], bfr[j], acc[i][j], 0, 0, 0);
    __builtin_amdgcn_s_setprio(0);
    asm volatile("s_barrier" ::: "memory");
  }
  __syncthreads();
  if (isQ) {
#pragma unroll
    for (int i = 0; i < 4; i++)
#pragma unroll
      for (int j = 0; j < 4; j++) {
        size_t row = (size_t)by * 128 + wr + i * 16 + quad * 4;
        size_t col = (size_t)bx * 128 + wc + j * 16 + l16;
#pragma unroll
        for (int r = 0; r < 4; r++)
          qb[(row + r) * 1024 + col] = f2bf(acc[i][j][r]);
      }
  } else if (bx < 8) {
    // K region: head-major kb[b][h=bx][l][128]
#pragma unroll
    for (int i = 0; i < 4; i++)
#pragma unroll
      for (int j = 0; j < 4; j++) {
        int rowg = by * 128 + wr + i * 16 + quad * 4; // global ctx row
        int bb = rowg >> 12, l = rowg & 4095;
        int c = wc + j * 16 + l16;
        uint16_t* dst = kb + (((size_t)(bb * 8 + bx) * 4096 + l) * 128 + c);
#pragma unroll
        for (int r = 0; r < 4; r++)
          dst[r * 128] = f2bf(acc[i][j][r]);
      }
  } else {
    // V region: tile = head (bx-8); bounce col-major through LDS, wide stores
    const int bh = (by >> 5) * 8 + (bx - 8);
    const int lbase = (by & 31) * 128;
    uint16_t* vdst = vtb + (size_t)bh * 524288;
#pragma unroll
    for (int half = 0; half < 2; half++) {
      if (wr == half * 64) {
#pragma unroll
        for (int i = 0; i < 4; i++)
#pragma unroll
          for (int j = 0; j < 4; j++) {
            int rowl = i * 16 + quad * 4;
            int col = wc + j * 16 + l16;
            union { uint64_t q; uint16_t u[4]; } pk;
#pragma unroll
            for (int r = 0; r < 4; r++) pk.u[r] = f2bf(acc[i][j][r]);
            *(uint64_t*)&smem[col * 72 + rowl] = pk.q;
          }
      }
      __syncthreads();
      {
        int col = tid >> 1, rseg = (tid & 1) * 32;
        const uint16_t* src = &smem[col * 72 + rseg];
        uint16_t* d = vdst + (size_t)col * 4096 + lbase + half * 64 + rseg;
#pragma unroll
        for (int k = 0; k < 4; k++)
          ((uint4*)d)[k] = *(const uint4*)&src[k * 8];
      }
      __syncthreads();
    }
  }
}

// ---------------- output GEMM: out = attb @ woutt + bias, 128^2 tile (R10b loop) ----------------
// R15: replaces the 64^2-tile k_gemm64 — 16 MFMA per 8 ds_read per K-step
// (2x the MFMA:LDS ratio), 128 blocks XCD-swizzled, f32 epilogue with bias.
__global__ __launch_bounds__(256, 4) void k_gemm_out(const uint16_t* __restrict__ attb,
                                                     const uint16_t* __restrict__ woutt,
                                                     float* __restrict__ Cf,
                                                     const float* __restrict__ bias) {
  __shared__ uint16_t smem[16384]; // 2 slots x (A 4096 + B 4096)
  const int K = 1024;
  const int tid = threadIdx.x;
  const int lane = tid & 63, w = tid >> 6;
  const int quad = lane >> 4, l16 = lane & 15;
  const int wr = (w >> 1) * 64, wc = (w & 1) * 64;
  int id = blockIdx.x;
  int xcd = id & 7, t = id >> 3;         // t in [0,16)
  int by = (xcd << 1) + (t & 1);         // 16 M-panels (2048 rows)
  int bx = t >> 1;                       // 8 N-panels (1024 cols)
  const uint16_t* Ab = attb + (size_t)by * 128 * K;
  const uint16_t* Bb = woutt + (size_t)bx * 128 * K;
  f32x4 acc[4][4] = {};
  const int rA = tid >> 2, slotA = tid & 3;
  const int rA1 = rA + 64;
  const int segA0 = (slotA ^ ((rA + (rA >> 2)) & 3)) * 8;
  const int segA1 = (slotA ^ ((rA1 + (rA1 >> 2)) & 3)) * 8;
  const uint16_t* gA0 = Ab + (size_t)rA * K + segA0;
  const uint16_t* gA1 = Ab + (size_t)rA1 * K + segA1;
  const uint16_t* gB0 = Bb + (size_t)rA * K + segA0;
  const uint16_t* gB1 = Bb + (size_t)rA1 * K + segA1;
  load_lds16(gA0, smem + tid * 8);
  load_lds16(gA1, smem + (tid + 256) * 8);
  load_lds16(gB0, smem + (tid + 512) * 8);
  load_lds16(gB1, smem + (tid + 768) * 8);
  for (int t2 = 0; t2 < 32; ++t2) {
    const uint16_t* la = smem + (t2 & 1) * 8192;
    const uint16_t* lb = la + 4096;
    if (t2 < 31) {
      uint16_t* ln = smem + ((t2 + 1) & 1) * 8192;
      const int k1 = (t2 + 1) * 32;
      load_lds16(gA0 + k1, ln + tid * 8);
      load_lds16(gA1 + k1, ln + (tid + 256) * 8);
      load_lds16(gB0 + k1, ln + (tid + 512) * 8);
      load_lds16(gB1 + k1, ln + (tid + 768) * 8);
      asm volatile("s_waitcnt vmcnt(4)\n\ts_barrier" ::: "memory");
    } else {
      asm volatile("s_waitcnt vmcnt(0)\n\ts_barrier" ::: "memory");
    }
    bf16x8 af[4], bfr[4];
#pragma unroll
    for (int i = 0; i < 4; i++) {
      int R = wr + i * 16 + l16;
      int s = quad ^ ((R + (R >> 2)) & 3);
      af[i] = *(const bf16x8*)&la[R * 32 + s * 8];
    }
#pragma unroll
    for (int j = 0; j < 4; j++) {
      int R = wc + j * 16 + l16;
      int s = quad ^ ((R + (R >> 2)) & 3);
      bfr[j] = *(const bf16x8*)&lb[R * 32 + s * 8];
    }
    __builtin_amdgcn_s_setprio(1);
#pragma unroll
    for (int i = 0; i < 4; i++)
#pragma unroll
      for (int j = 0; j < 4; j++)
        acc[i][j] = __builtin_amdgcn_mfma_f32_16x16x32_bf16(af[i], bfr[j], acc[i][j], 0, 0, 0);
    __builtin_amdgcn_s_setprio(0);
    asm volatile("s_barrier" ::: "memory");
  }
#pragma unroll
  for (int i = 0; i < 4; i++)
#pragma unroll
    for (int j = 0; j < 4; j++) {
      size_t row = (size_t)by * 128 + wr + i * 16 + quad * 4;
      size_t col = (size_t)bx * 128 + wc + j * 16 + l16;
      float bv = bias[col];
#pragma unroll
      for (int r = 0; r < 4; r++)
        Cf[(row + r) * 1024 + col] = acc[i][j][r] + bv;
    }
}

// ---------------- flash attention, key-split x4 (one doc per split) ----------------
__global__ __launch_bounds__(256) void k_attn(const uint16_t* __restrict__ q,
                                              const uint16_t* __restrict__ kb,
                                              const uint16_t* __restrict__ vt,
                                              const float* __restrict__ sims,
                                              const float* __restrict__ beta,
                                              uint16_t* __restrict__ po,
                                              float* __restrict__ pl) {
  __shared__ uint16_t Kl[2][8192]; // 64 keys x 128 hd, seg-swizzled (2x16 KB)
  __shared__ uint16_t Vl[2][8192]; // 128 d x 64 keys, seg-swizzled (2x16 KB)
  const int idx = blockIdx.x;
  const int qbx = idx >> 6, g = idx & 63;
  const int h = g >> 3, b = (g >> 2) & 1, sp = g & 3;
  const int q0 = qbx * 128;
  const int tid = threadIdx.x, lane = tid & 63, w = tid >> 6;
  const int quad = lane >> 4, l16 = lane & 15;
  const float wsplit =
      __builtin_amdgcn_exp2f(sims[b * 4 + sp] * beta[0] * 1.44269504f);

  union { uint32_t u[4]; bf16x8 v; } Oc;
#pragma unroll
  for (int j = 0; j < 4; j++) Oc.u[j] = 0x3F803F80u;
  const bf16x8 onesf = Oc.v;

  bf16x8 qf[2][4];
#pragma unroll
  for (int rb = 0; rb < 2; rb++) {
    const uint16_t* qrow =
        q + ((size_t)(b * 1024 + q0 + w * 32 + rb * 16 + l16)) * 1024 + h * 128 + quad * 8;
#pragma unroll
    for (int ks = 0; ks < 4; ks++) qf[rb][ks] = *(const bf16x8*)(qrow + ks * 32);
  }
  f32x4 o[2][8] = {};
  f32x4 o9[2] = {};

  const uint16_t* kptr = kb + ((size_t)(b * 8 + h) * 4096 + sp * 1024) * 128;
  const uint16_t* vptr = vt + ((size_t)(b * 8 + h) * 128) * 4096 + sp * 1024;

  // prologue: stage chunk 0 into slot 0
#pragma unroll
  for (int ii = 0; ii < 4; ii++) {
    int g2 = tid + ii * 256;
    int row = g2 >> 4, seg = (g2 & 15) ^ (row & 15);
    load_lds16(kptr + row * 128 + seg * 8, &Kl[0][g2 * 8]);
  }
#pragma unroll
  for (int ii = 0; ii < 4; ii++) {
    int g2 = tid + ii * 256;
    int row = g2 >> 3, seg = (g2 & 7) ^ (row & 7);
    load_lds16(vptr + (size_t)row * 4096 + seg * 8, &Vl[0][g2 * 8]);
  }

  for (int c = 0; c < 16; c++) {
    const uint16_t* Kc = Kl[c & 1];
    const uint16_t* Vc = Vl[c & 1];
    if (c < 15) {
      const uint16_t* kn = kptr + 64 * 128;
      const uint16_t* vn = vptr + 64;
      uint16_t* Kd = Kl[(c + 1) & 1];
      uint16_t* Vd = Vl[(c + 1) & 1];
#pragma unroll
      for (int ii = 0; ii < 4; ii++) {
        int g2 = tid + ii * 256;
        int row = g2 >> 4, seg = (g2 & 15) ^ (row & 15);
        load_lds16(kn + row * 128 + seg * 8, Kd + g2 * 8);
      }
#pragma unroll
      for (int ii = 0; ii < 4; ii++) {
        int g2 = tid + ii * 256;
        int row = g2 >> 3, seg = (g2 & 7) ^ (row & 7);
        load_lds16(vn + (size_t)row * 4096 + seg * 8, Vd + g2 * 8);
      }
      asm volatile("s_waitcnt vmcnt(8)\n\ts_barrier" ::: "memory");
    } else {
      asm volatile("s_waitcnt vmcnt(0)\n\ts_barrier" ::: "memory");
    }
#pragma unroll
    for (int kh = 0; kh < 2; kh++) {
      // swapped QK: C col=l16=q, row=quad*4+r=key (key = nb*16 + quad*4 + r)
      f32x4 s[2][2] = {{{0.f,0.f,0.f,0.f},{0.f,0.f,0.f,0.f}},
                       {{0.f,0.f,0.f,0.f},{0.f,0.f,0.f,0.f}}};
      __builtin_amdgcn_s_setprio(1);
#pragma unroll
      for (int nb2 = 0; nb2 < 2; nb2++) {
        const int nb = kh * 2 + nb2;
#pragma unroll
        for (int ks = 0; ks < 4; ks++) {
          bf16x8 kf = *(const bf16x8*)&Kc[(nb * 16 + l16) * 128 + (((ks * 4 + quad) ^ l16) * 8)];
          s[nb2][0] = __builtin_amdgcn_mfma_f32_16x16x32_bf16(kf, qf[0][ks], s[nb2][0], 0, 0, 0);
          s[nb2][1] = __builtin_amdgcn_mfma_f32_16x16x32_bf16(kf, qf[1][ks], s[nb2][1], 0, 0, 0);
        }
      }
      __builtin_amdgcn_s_setprio(0);
      // exp2 + pack + cross-quad redistribution -> PV A-frags, all in registers.
      bf16x8 pa[2];
#pragma unroll
      for (int qh = 0; qh < 2; qh++) {
        uint32_t a0 = cvtpk_bf16(__builtin_amdgcn_exp2f(s[0][qh][0]),
                                 __builtin_amdgcn_exp2f(s[0][qh][1]));
        uint32_t a1 = cvtpk_bf16(__builtin_amdgcn_exp2f(s[0][qh][2]),
                                 __builtin_amdgcn_exp2f(s[0][qh][3]));
        uint32_t b0 = cvtpk_bf16(__builtin_amdgcn_exp2f(s[1][qh][0]),
                                 __builtin_amdgcn_exp2f(s[1][qh][1]));
        uint32_t b1 = cvtpk_bf16(__builtin_amdgcn_exp2f(s[1][qh][2]),
                                 __builtin_amdgcn_exp2f(s[1][qh][3]));
        swap_half32(a0, b0);
        swap_half16(a0, b0);
        swap_half32(a1, b1);
        swap_half16(a1, b1);
        union { uint32_t u[4]; bf16x8 v; } pk_;
        pk_.u[0] = a0; pk_.u[1] = a1; pk_.u[2] = b0; pk_.u[3] = b1;
        pa[qh] = pk_.v;
      }
      // PV for this half
      const int sq = ((kh * 4 + quad) ^ (l16 & 7)) * 8;
      __builtin_amdgcn_s_setprio(1);
#pragma unroll
      for (int nb = 0; nb < 8; nb++) {
        bf16x8 vf = *(const bf16x8*)&Vc[(nb * 16 + l16) * 64 + sq];
        o[0][nb] = __builtin_amdgcn_mfma_f32_16x16x32_bf16(pa[0], vf, o[0][nb], 0, 0, 0);
        o[1][nb] = __builtin_amdgcn_mfma_f32_16x16x32_bf16(pa[1], vf, o[1][nb], 0, 0, 0);
      }
      o9[0] = __builtin_amdgcn_mfma_f32_16x16x32_bf16(pa[0], onesf, o9[0], 0, 0, 0);
      o9[1] = __builtin_amdgcn_mfma_f32_16x16x32_bf16(pa[1], onesf, o9[1], 0, 0, 0);
      __builtin_amdgcn_s_setprio(0);
    }
    asm volatile("s_barrier" ::: "memory"); // WAR guard before next restage
    kptr += 64 * 128;
    vptr += 64;
  }
  // epilogue: sim-weighted partial O (bf16) + weighted row sums
  const int rowbase = (sp * 16 + b * 8 + h) * 1024 + q0 + w * 32;
#pragma unroll
  for (int rb = 0; rb < 2; rb++)
#pragma unroll
    for (int r = 0; r < 4; r++) {
      int row = rowbase + rb * 16 + quad * 4 + r;
#pragma unroll
      for (int nb = 0; nb < 8; nb++)
        po[(size_t)row * 128 + nb * 16 + l16] = f2bf(o[rb][nb][r] * wsplit);
      if (l16 == 0)
        pl[row] = o9[rb][r] * wsplit;
    }
}

// ---------------- merge 4 key-split partials (plain weighted sum) -> attb ----------------
__global__ __launch_bounds__(256) void k_merge(const uint16_t* __restrict__ po,
                                               const float* __restrict__ pl,
                                               uint16_t* __restrict__ attb) {
  const int bq = blockIdx.x;
  const int b = bq >> 10, qi = bq & 1023;
  const int t = threadIdx.x;
  const int h = t >> 5, d0 = (t & 31) * 4;
  const int bh = b * 8 + h;
  float den = 0.f;
  float acc[4] = {0.f, 0.f, 0.f, 0.f};
#pragma unroll
  for (int s = 0; s < 4; s++) {
    den += pl[(s * 16 + bh) * 1024 + qi];
    union { uint64_t q; uint16_t u[4]; } v;
    v.q = *(const uint64_t*)&po[(((size_t)(s * 16 + bh)) * 1024 + qi) * 128 + d0];
#pragma unroll
    for (int j = 0; j < 4; j++) acc[j] += bf2f(v.u[j]);
  }
  const float inv = 1.0f / den;
  union { uint64_t q; uint16_t u[4]; } o;
#pragma unroll
  for (int j = 0; j < 4; j++) o.u[j] = f2bf(acc[j] * inv);
  *(uint64_t*)&attb[((size_t)(b * 1024 + qi)) * 1024 + h * 128 + d0] = o.q;
}

// ---------------- launch ----------------
extern "C" void kernel_launch(void* const* d_in, const int* in_sizes, int n_in,
                              void* d_out, int out_size, void* d_ws, size_t ws_size,
                              hipStream_t stream) {
  (void)in_sizes; (void)n_in; (void)out_size; (void)ws_size;
  const float* x    = (const float*)d_in[0];
  const float* ctx  = (const float*)d_in[1];
  const float* sims = (const float*)d_in[2];
  const float* Wq   = (const float*)d_in[3];
  const float* Wkv  = (const float*)d_in[4];
  const float* beta = (const float*)d_in[5];
  const float* Wout = (const float*)d_in[6];
  const float* bout = (const float*)d_in[7];
  float* out = (float*)d_out;

  char* ws = (char*)d_ws;
  uint16_t* xb    = (uint16_t*)(ws + 0);           // 4 MB  (dead after fused GEMM)
  uint16_t* ctxb  = (uint16_t*)(ws + (4u << 20));  // 16 MB (dead after fused GEMM)
  uint16_t* wqt   = (uint16_t*)(ws + (20u << 20)); // 2 MB  (dead after fused GEMM)
  uint16_t* wkvt  = (uint16_t*)(ws + (22u << 20)); // 4 MB  (dead after fused GEMM)
  uint16_t* kb    = (uint16_t*)(ws + (32u << 20)); // 16 MB [2][8][4096][128]
  uint16_t* vtb   = (uint16_t*)(ws + (48u << 20)); // 16 MB [16][128][4096]
  float*    pl    = (float*)   (ws + (64u << 20)); // 256 KB used [64][1024]
  uint16_t* woutt = (uint16_t*)(ws + (68u << 20)); // 2 MB (live till end)
  uint16_t* qb    = (uint16_t*)(ws + (70u << 20)); // 4 MB (live till attn)
  uint16_t* attb  = (uint16_t*)(ws + (74u << 20)); // 4 MB
  // po (16 MB) reuses 0..16 MB: xb/ctxb dead by attention time
  uint16_t* po = (uint16_t*)(ws + 0);              // 16 MB [64][1024][128]

  const float LOG2E = 1.44269504f;
  const float qscale = 0.03125f * LOG2E;

  k_prep<<<14336, 256, 0, stream>>>(x, ctx, Wq, Wkv, Wout, xb, ctxb, wqt, wkvt, woutt, qscale);
  k_gemm_fused<<<1152, 256, 0, stream>>>(ctxb, wkvt, xb, wqt, kb, vtb, qb);
  k_attn<<<512, 256, 0, stream>>>(qb, kb, vtb, sims, beta, po, pl);
  k_merge<<<2048, 256, 0, stream>>>(po, pl, attb);
  k_gemm_out<<<128, 256, 0, stream>>>(attb, woutt, out, bout);
}

// Round 11
// 205.639 us; speedup vs baseline: 1.5982x; 1.0795x over previous
//
#include <hip/hip_runtime.h>
#include <stdint.h>

typedef __attribute__((ext_vector_type(4))) float f32x4;
typedef __attribute__((ext_vector_type(8))) __bf16 bf16x8;
typedef __attribute__((ext_vector_type(2))) unsigned int u32x2;

__device__ __forceinline__ uint16_t f2bf(float f) {
  uint32_t u = __builtin_bit_cast(uint32_t, f);
  u += 0x7FFFu + ((u >> 16) & 1u);
  return (uint16_t)(u >> 16);
}

__device__ __forceinline__ float bf2f(uint16_t u) {
  uint32_t v = ((uint32_t)u) << 16;
  return __builtin_bit_cast(float, v);
}

__device__ __forceinline__ uint32_t cvtpk_bf16(float lo, float hi) {
  uint32_t r;
  asm("v_cvt_pk_bf16_f32 %0, %1, %2" : "=v"(r) : "v"(lo), "v"(hi));
  return r;
}

// swap halves: a[32:63] <-> b[0:31]
__device__ __forceinline__ void swap_half32(uint32_t& a, uint32_t& b) {
#if __has_builtin(__builtin_amdgcn_permlane32_swap)
  u32x2 r = __builtin_amdgcn_permlane32_swap(a, b, false, false);
  a = r[0]; b = r[1];
#else
  int lane = __builtin_amdgcn_mbcnt_hi(~0u, __builtin_amdgcn_mbcnt_lo(~0u, 0));
  uint32_t ax = (uint32_t)__shfl_xor((int)a, 32, 64);
  uint32_t bx = (uint32_t)__shfl_xor((int)b, 32, 64);
  uint32_t an = (lane < 32) ? a : bx;
  uint32_t bn = (lane < 32) ? ax : b;
  a = an; b = bn;
#endif
}

// swap 16-lane rows: a[16:31]<->b[0:15], a[48:63]<->b[32:47]
__device__ __forceinline__ void swap_half16(uint32_t& a, uint32_t& b) {
#if __has_builtin(__builtin_amdgcn_permlane16_swap)
  u32x2 r = __builtin_amdgcn_permlane16_swap(a, b, false, false);
  a = r[0]; b = r[1];
#else
  int lane = __builtin_amdgcn_mbcnt_hi(~0u, __builtin_amdgcn_mbcnt_lo(~0u, 0));
  uint32_t ax = (uint32_t)__shfl_xor((int)a, 16, 64);
  uint32_t bx = (uint32_t)__shfl_xor((int)b, 16, 64);
  uint32_t an = ((lane & 16) == 0) ? a : bx;
  uint32_t bn = ((lane & 16) == 0) ? ax : b;
  a = an; b = bn;
#endif
}

__device__ __forceinline__ void load_lds16(const uint16_t* g, uint16_t* l) {
  __builtin_amdgcn_global_load_lds((const __attribute__((address_space(1))) void*)g,
                                   (__attribute__((address_space(3))) void*)l, 16, 0, 0);
}

// ---------------- fused prep: convert x+ctx to bf16, transpose 3 W's ----------------
__global__ __launch_bounds__(256) void k_prep(const float* __restrict__ x,
                                              const float* __restrict__ ctx,
                                              const float* __restrict__ Wq,
                                              const float* __restrict__ Wkv,
                                              const float* __restrict__ Wout,
                                              uint16_t* __restrict__ xb,
                                              uint16_t* __restrict__ ctxb,
                                              uint16_t* __restrict__ wqt,
                                              uint16_t* __restrict__ wkvt,
                                              uint16_t* __restrict__ woutt,
                                              float qscale) {
  __shared__ float tile[32][33];
  int id = blockIdx.x;
  int tid = threadIdx.x;
  if (id < 10240) {
    const float* in;
    uint16_t* out;
    int j = id * 256 + tid;
    if (j < 524288) { in = x; out = xb; }
    else            { in = ctx; out = ctxb; j -= 524288; }
    float4 v = ((const float4*)in)[j];
    union { uint16_t u[4]; uint64_t q; } o;
    o.u[0] = f2bf(v.x); o.u[1] = f2bf(v.y); o.u[2] = f2bf(v.z); o.u[3] = f2bf(v.w);
    ((uint64_t*)out)[j] = o.q;
    return;
  }
  id -= 10240;
  const float* W;
  uint16_t* Wt;
  int N, n0, k0;
  float sc = 1.0f;
  if (id < 1024)      { W = Wq;   Wt = wqt;   N = 1024; sc = qscale;
                        n0 = (id & 31) * 32; k0 = (id >> 5) * 32; }
  else if (id < 2048) { W = Wout; Wt = woutt; N = 1024; id -= 1024;
                        n0 = (id & 31) * 32; k0 = (id >> 5) * 32; }
  else                { W = Wkv;  Wt = wkvt;  N = 2048; id -= 2048;
                        n0 = (id & 63) * 32; k0 = (id >> 6) * 32; }
  int c = tid & 31, r0 = tid >> 5;
#pragma unroll
  for (int i = 0; i < 4; i++) {
    int r = r0 + i * 8;
    tile[r][c] = W[(size_t)(k0 + r) * N + n0 + c];
  }
  __syncthreads();
#pragma unroll
  for (int i = 0; i < 4; i++) {
    int r = r0 + i * 8;
    Wt[(size_t)(n0 + r) * 1024 + k0 + c] = f2bf(tile[c][r] * sc);
  }
}

// ---------------- fused GEMM: kv = ctx @ Wkv (K->kb head-major, V->vtb^T) and q = x @ Wq' ----------------
// R10b structure (proven fastest): 2-slot double-buffered LDS + counted vmcnt(4).
__global__ __launch_bounds__(256, 4) void k_gemm_fused(const uint16_t* __restrict__ ctxb,
                                                       const uint16_t* __restrict__ wkvt,
                                                       const uint16_t* __restrict__ xb,
                                                       const uint16_t* __restrict__ wqt,
                                                       uint16_t* __restrict__ kb,
                                                       uint16_t* __restrict__ vtb,
                                                       uint16_t* __restrict__ qb) {
  __shared__ uint16_t smem[16384]; // 2 slots x (A 4096 + B 4096); V-epilogue reuses [0,9216)
  const int K = 1024;
  const int tid = threadIdx.x;
  const int lane = tid & 63, w = tid >> 6;
  const int quad = lane >> 4, l16 = lane & 15;
  const int wr = (w >> 1) * 64, wc = (w & 1) * 64;
  int id = blockIdx.x;
  int bx, by, isQ;
  const uint16_t *Ab, *Bb;
  if (id < 1024) {
    isQ = 0;
    int xcd = id & 7, t = id >> 3;         // t in [0,128)
    by = (xcd << 3) + (t & 7);             // 8 A-panels per XCD
    bx = t >> 3;                           // all 16 col tiles co-XCD
    Ab = ctxb + (size_t)by * 128 * K;
    Bb = wkvt + (size_t)bx * 128 * K;
  } else {
    isQ = 1; id -= 1024;
    int xcd = id & 7, t = id >> 3;         // t in [0,16)
    by = (xcd << 1) + (t & 1);             // 2 A-panels per XCD
    bx = t >> 1;
    Ab = xb + (size_t)by * 128 * K;
    Bb = wqt + (size_t)bx * 128 * K;
  }
  f32x4 acc[4][4] = {};
  const int rA = tid >> 2, slotA = tid & 3;
  const int rA1 = rA + 64;
  const int segA0 = (slotA ^ ((rA + (rA >> 2)) & 3)) * 8;
  const int segA1 = (slotA ^ ((rA1 + (rA1 >> 2)) & 3)) * 8;
  const uint16_t* gA0 = Ab + (size_t)rA * K + segA0;
  const uint16_t* gA1 = Ab + (size_t)rA1 * K + segA1;
  const uint16_t* gB0 = Bb + (size_t)rA * K + segA0;
  const uint16_t* gB1 = Bb + (size_t)rA1 * K + segA1;
  // prologue: stage tile 0 into slot 0
  load_lds16(gA0, smem + tid * 8);
  load_lds16(gA1, smem + (tid + 256) * 8);
  load_lds16(gB0, smem + (tid + 512) * 8);
  load_lds16(gB1, smem + (tid + 768) * 8);
  for (int t = 0; t < 32; ++t) {
    const uint16_t* la = smem + (t & 1) * 8192;
    const uint16_t* lb = la + 4096;
    if (t < 31) {
      uint16_t* ln = smem + ((t + 1) & 1) * 8192;
      const int k1 = (t + 1) * 32;
      load_lds16(gA0 + k1, ln + tid * 8);
      load_lds16(gA1 + k1, ln + (tid + 256) * 8);
      load_lds16(gB0 + k1, ln + (tid + 512) * 8);
      load_lds16(gB1 + k1, ln + (tid + 768) * 8);
      asm volatile("s_waitcnt vmcnt(4)\n\ts_barrier" ::: "memory");
    } else {
      asm volatile("s_waitcnt vmcnt(0)\n\ts_barrier" ::: "memory");
    }
    bf16x8 af[4], bfr[4];
#pragma unroll
    for (int i = 0; i < 4; i++) {
      int R = wr + i * 16 + l16;
      int s = quad ^ ((R + (R >> 2)) & 3);
      af[i] = *(const bf16x8*)&la[R * 32 + s * 8];
    }
#pragma unroll
    for (int j = 0; j < 4; j++) {
      int R = wc + j * 16 + l16;
      int s = quad ^ ((R + (R >> 2)) & 3);
      bfr[j] = *(const bf16x8*)&lb[R * 32 + s * 8];
    }
    __builtin_amdgcn_s_setprio(1);
#pragma unroll
    for (int i = 0; i < 4; i++)
#pragma unroll
      for (int j = 0; j < 4; j++)
        acc[i][j] = __builtin_amdgcn_mfma_f32_16x16x32_bf16(af[i], bfr[j], acc[i][j], 0, 0, 0);
    __builtin_amdgcn_s_setprio(0);
    asm volatile("s_barrier" ::: "memory");
  }
  __syncthreads();
  if (isQ) {
#pragma unroll
    for (int i = 0; i < 4; i++)
#pragma unroll
      for (int j = 0; j < 4; j++) {
        size_t row = (size_t)by * 128 + wr + i * 16 + quad * 4;
        size_t col = (size_t)bx * 128 + wc + j * 16 + l16;
#pragma unroll
        for (int r = 0; r < 4; r++)
          qb[(row + r) * 1024 + col] = f2bf(acc[i][j][r]);
      }
  } else if (bx < 8) {
    // K region: head-major kb[b][h=bx][l][128]
#pragma unroll
    for (int i = 0; i < 4; i++)
#pragma unroll
      for (int j = 0; j < 4; j++) {
        int rowg = by * 128 + wr + i * 16 + quad * 4; // global ctx row
        int bb = rowg >> 12, l = rowg & 4095;
        int c = wc + j * 16 + l16;
        uint16_t* dst = kb + (((size_t)(bb * 8 + bx) * 4096 + l) * 128 + c);
#pragma unroll
        for (int r = 0; r < 4; r++)
          dst[r * 128] = f2bf(acc[i][j][r]);
      }
  } else {
    // V region: tile = head (bx-8); bounce col-major through LDS, wide stores
    const int bh = (by >> 5) * 8 + (bx - 8);
    const int lbase = (by & 31) * 128;
    uint16_t* vdst = vtb + (size_t)bh * 524288;
#pragma unroll
    for (int half = 0; half < 2; half++) {
      if (wr == half * 64) {
#pragma unroll
        for (int i = 0; i < 4; i++)
#pragma unroll
          for (int j = 0; j < 4; j++) {
            int rowl = i * 16 + quad * 4;
            int col = wc + j * 16 + l16;
            union { uint64_t q; uint16_t u[4]; } pk;
#pragma unroll
            for (int r = 0; r < 4; r++) pk.u[r] = f2bf(acc[i][j][r]);
            *(uint64_t*)&smem[col * 72 + rowl] = pk.q;
          }
      }
      __syncthreads();
      {
        int col = tid >> 1, rseg = (tid & 1) * 32;
        const uint16_t* src = &smem[col * 72 + rseg];
        uint16_t* d = vdst + (size_t)col * 4096 + lbase + half * 64 + rseg;
#pragma unroll
        for (int k = 0; k < 4; k++)
          ((uint4*)d)[k] = *(const uint4*)&src[k * 8];
      }
      __syncthreads();
    }
  }
}

// ---------------- GEMM 64x64 tile, BK=64 (for out), dbuf + counted vmcnt ----------------
__global__ __launch_bounds__(256) void k_gemm64(const uint16_t* __restrict__ A,
                                                const uint16_t* __restrict__ Bt,
                                                float* __restrict__ Cf,
                                                const float* __restrict__ bias,
                                                int M, int N, int K) {
  __shared__ uint16_t smem[16384]; // 2 slots x (A 4096 + B 4096)
  const int tid = threadIdx.x;
  const int lane = tid & 63, w = tid >> 6;
  const int quad = lane >> 4, l16 = lane & 15;
  const int wr = (w >> 1) * 32, wc = (w & 1) * 32;
  const size_t tr0 = (size_t)blockIdx.y * 64, tc0 = (size_t)blockIdx.x * 64;
  f32x4 acc[2][2] = {};
  const int rS = tid >> 3, sS = tid & 7;
  const int seg = (sS ^ (rS & 7)) * 8;
  const uint16_t* Ab = A + tr0 * K;
  const uint16_t* Bb = Bt + tc0 * K;
  const uint16_t* gA0 = Ab + (size_t)rS * K + seg;
  const uint16_t* gA1 = Ab + (size_t)(rS + 32) * K + seg;
  const uint16_t* gB0 = Bb + (size_t)rS * K + seg;
  const uint16_t* gB1 = Bb + (size_t)(rS + 32) * K + seg;
  const int NT = K >> 6;
  load_lds16(gA0, smem + tid * 8);
  load_lds16(gA1, smem + (tid + 256) * 8);
  load_lds16(gB0, smem + (tid + 512) * 8);
  load_lds16(gB1, smem + (tid + 768) * 8);
  for (int t = 0; t < NT; ++t) {
    const uint16_t* la = smem + (t & 1) * 8192;
    const uint16_t* lb = la + 4096;
    if (t < NT - 1) {
      uint16_t* ln = smem + ((t + 1) & 1) * 8192;
      const int k1 = (t + 1) * 64;
      load_lds16(gA0 + k1, ln + tid * 8);
      load_lds16(gA1 + k1, ln + (tid + 256) * 8);
      load_lds16(gB0 + k1, ln + (tid + 512) * 8);
      load_lds16(gB1 + k1, ln + (tid + 768) * 8);
      asm volatile("s_waitcnt vmcnt(4)\n\ts_barrier" ::: "memory");
    } else {
      asm volatile("s_waitcnt vmcnt(0)\n\ts_barrier" ::: "memory");
    }
    __builtin_amdgcn_s_setprio(1);
#pragma unroll
    for (int sub = 0; sub < 2; sub++) {
      const int kk = sub * 4 + quad;
      bf16x8 af[2], bfr[2];
#pragma unroll
      for (int i = 0; i < 2; i++) {
        int R = wr + i * 16 + l16;
        af[i] = *(const bf16x8*)&la[R * 64 + (kk ^ (R & 7)) * 8];
      }
#pragma unroll
      for (int j = 0; j < 2; j++) {
        int R = wc + j * 16 + l16;
        bfr[j] = *(const bf16x8*)&lb[R * 64 + (kk ^ (R & 7)) * 8];
      }
#pragma unroll
      for (int i = 0; i < 2; i++)
#pragma unroll
        for (int j = 0; j < 2; j++)
          acc[i][j] = __builtin_amdgcn_mfma_f32_16x16x32_bf16(af[i], bfr[j], acc[i][j], 0, 0, 0);
    }
    __builtin_amdgcn_s_setprio(0);
    asm volatile("s_barrier" ::: "memory");
  }
#pragma unroll
  for (int i = 0; i < 2; i++) {
#pragma unroll
    for (int j = 0; j < 2; j++) {
      size_t row = tr0 + wr + i * 16 + quad * 4;
      size_t col = tc0 + wc + j * 16 + l16;
#pragma unroll
      for (int r = 0; r < 4; r++)
        Cf[(row + r) * N + col] = acc[i][j][r] + bias[col];
    }
  }
}

// ---------------- flash attention, key-split x4 (one doc per split) ----------------
__global__ __launch_bounds__(256) void k_attn(const uint16_t* __restrict__ q,
                                              const uint16_t* __restrict__ kb,
                                              const uint16_t* __restrict__ vt,
                                              const float* __restrict__ sims,
                                              const float* __restrict__ beta,
                                              uint16_t* __restrict__ po,
                                              float* __restrict__ pl) {
  __shared__ uint16_t Kl[2][8192]; // 64 keys x 128 hd, seg-swizzled (2x16 KB)
  __shared__ uint16_t Vl[2][8192]; // 128 d x 64 keys, seg-swizzled (2x16 KB)
  const int idx = blockIdx.x;
  const int qbx = idx >> 6, g = idx & 63;
  const int h = g >> 3, b = (g >> 2) & 1, sp = g & 3;
  const int q0 = qbx * 128;
  const int tid = threadIdx.x, lane = tid & 63, w = tid >> 6;
  const int quad = lane >> 4, l16 = lane & 15;
  const float wsplit =
      __builtin_amdgcn_exp2f(sims[b * 4 + sp] * beta[0] * 1.44269504f);

  union { uint32_t u[4]; bf16x8 v; } Oc;
#pragma unroll
  for (int j = 0; j < 4; j++) Oc.u[j] = 0x3F803F80u;
  const bf16x8 onesf = Oc.v;

  bf16x8 qf[2][4];
#pragma unroll
  for (int rb = 0; rb < 2; rb++) {
    const uint16_t* qrow =
        q + ((size_t)(b * 1024 + q0 + w * 32 + rb * 16 + l16)) * 1024 + h * 128 + quad * 8;
#pragma unroll
    for (int ks = 0; ks < 4; ks++) qf[rb][ks] = *(const bf16x8*)(qrow + ks * 32);
  }
  f32x4 o[2][8] = {};
  f32x4 o9[2] = {};

  const uint16_t* kptr = kb + ((size_t)(b * 8 + h) * 4096 + sp * 1024) * 128;
  const uint16_t* vptr = vt + ((size_t)(b * 8 + h) * 128) * 4096 + sp * 1024;

  // prologue: stage chunk 0 into slot 0
#pragma unroll
  for (int ii = 0; ii < 4; ii++) {
    int g2 = tid + ii * 256;
    int row = g2 >> 4, seg = (g2 & 15) ^ (row & 15);
    load_lds16(kptr + row * 128 + seg * 8, &Kl[0][g2 * 8]);
  }
#pragma unroll
  for (int ii = 0; ii < 4; ii++) {
    int g2 = tid + ii * 256;
    int row = g2 >> 3, seg = (g2 & 7) ^ (row & 7);
    load_lds16(vptr + (size_t)row * 4096 + seg * 8, &Vl[0][g2 * 8]);
  }

  for (int c = 0; c < 16; c++) {
    const uint16_t* Kc = Kl[c & 1];
    const uint16_t* Vc = Vl[c & 1];
    if (c < 15) {
      const uint16_t* kn = kptr + 64 * 128;
      const uint16_t* vn = vptr + 64;
      uint16_t* Kd = Kl[(c + 1) & 1];
      uint16_t* Vd = Vl[(c + 1) & 1];
#pragma unroll
      for (int ii = 0; ii < 4; ii++) {
        int g2 = tid + ii * 256;
        int row = g2 >> 4, seg = (g2 & 15) ^ (row & 15);
        load_lds16(kn + row * 128 + seg * 8, Kd + g2 * 8);
      }
#pragma unroll
      for (int ii = 0; ii < 4; ii++) {
        int g2 = tid + ii * 256;
        int row = g2 >> 3, seg = (g2 & 7) ^ (row & 7);
        load_lds16(vn + (size_t)row * 4096 + seg * 8, Vd + g2 * 8);
      }
      asm volatile("s_waitcnt vmcnt(8)\n\ts_barrier" ::: "memory");
    } else {
      asm volatile("s_waitcnt vmcnt(0)\n\ts_barrier" ::: "memory");
    }
#pragma unroll
    for (int kh = 0; kh < 2; kh++) {
      // swapped QK: C col=l16=q, row=quad*4+r=key (key = nb*16 + quad*4 + r)
      f32x4 s[2][2] = {{{0.f,0.f,0.f,0.f},{0.f,0.f,0.f,0.f}},
                       {{0.f,0.f,0.f,0.f},{0.f,0.f,0.f,0.f}}};
      __builtin_amdgcn_s_setprio(1);
#pragma unroll
      for (int nb2 = 0; nb2 < 2; nb2++) {
        const int nb = kh * 2 + nb2;
#pragma unroll
        for (int ks = 0; ks < 4; ks++) {
          bf16x8 kf = *(const bf16x8*)&Kc[(nb * 16 + l16) * 128 + (((ks * 4 + quad) ^ l16) * 8)];
          s[nb2][0] = __builtin_amdgcn_mfma_f32_16x16x32_bf16(kf, qf[0][ks], s[nb2][0], 0, 0, 0);
          s[nb2][1] = __builtin_amdgcn_mfma_f32_16x16x32_bf16(kf, qf[1][ks], s[nb2][1], 0, 0, 0);
        }
      }
      __builtin_amdgcn_s_setprio(0);
      // exp2 + pack + cross-quad redistribution -> PV A-frags, all in registers.
      bf16x8 pa[2];
#pragma unroll
      for (int qh = 0; qh < 2; qh++) {
        uint32_t a0 = cvtpk_bf16(__builtin_amdgcn_exp2f(s[0][qh][0]),
                                 __builtin_amdgcn_exp2f(s[0][qh][1]));
        uint32_t a1 = cvtpk_bf16(__builtin_amdgcn_exp2f(s[0][qh][2]),
                                 __builtin_amdgcn_exp2f(s[0][qh][3]));
        uint32_t b0 = cvtpk_bf16(__builtin_amdgcn_exp2f(s[1][qh][0]),
                                 __builtin_amdgcn_exp2f(s[1][qh][1]));
        uint32_t b1 = cvtpk_bf16(__builtin_amdgcn_exp2f(s[1][qh][2]),
                                 __builtin_amdgcn_exp2f(s[1][qh][3]));
        swap_half32(a0, b0);
        swap_half16(a0, b0);
        swap_half32(a1, b1);
        swap_half16(a1, b1);
        union { uint32_t u[4]; bf16x8 v; } pk_;
        pk_.u[0] = a0; pk_.u[1] = a1; pk_.u[2] = b0; pk_.u[3] = b1;
        pa[qh] = pk_.v;
      }
      // PV for this half
      const int sq = ((kh * 4 + quad) ^ (l16 & 7)) * 8;
      __builtin_amdgcn_s_setprio(1);
#pragma unroll
      for (int nb = 0; nb < 8; nb++) {
        bf16x8 vf = *(const bf16x8*)&Vc[(nb * 16 + l16) * 64 + sq];
        o[0][nb] = __builtin_amdgcn_mfma_f32_16x16x32_bf16(pa[0], vf, o[0][nb], 0, 0, 0);
        o[1][nb] = __builtin_amdgcn_mfma_f32_16x16x32_bf16(pa[1], vf, o[1][nb], 0, 0, 0);
      }
      o9[0] = __builtin_amdgcn_mfma_f32_16x16x32_bf16(pa[0], onesf, o9[0], 0, 0, 0);
      o9[1] = __builtin_amdgcn_mfma_f32_16x16x32_bf16(pa[1], onesf, o9[1], 0, 0, 0);
      __builtin_amdgcn_s_setprio(0);
    }
    asm volatile("s_barrier" ::: "memory"); // WAR guard before next restage
    kptr += 64 * 128;
    vptr += 64;
  }
  // epilogue: sim-weighted partial O (bf16) + weighted row sums
  const int rowbase = (sp * 16 + b * 8 + h) * 1024 + q0 + w * 32;
#pragma unroll
  for (int rb = 0; rb < 2; rb++)
#pragma unroll
    for (int r = 0; r < 4; r++) {
      int row = rowbase + rb * 16 + quad * 4 + r;
#pragma unroll
      for (int nb = 0; nb < 8; nb++)
        po[(size_t)row * 128 + nb * 16 + l16] = f2bf(o[rb][nb][r] * wsplit);
      if (l16 == 0)
        pl[row] = o9[rb][r] * wsplit;
    }
}

// ---------------- merge 4 key-split partials (plain weighted sum) -> attb ----------------
__global__ __launch_bounds__(256) void k_merge(const uint16_t* __restrict__ po,
                                               const float* __restrict__ pl,
                                               uint16_t* __restrict__ attb) {
  const int bq = blockIdx.x;
  const int b = bq >> 10, qi = bq & 1023;
  const int t = threadIdx.x;
  const int h = t >> 5, d0 = (t & 31) * 4;
  const int bh = b * 8 + h;
  float den = 0.f;
  float acc[4] = {0.f, 0.f, 0.f, 0.f};
#pragma unroll
  for (int s = 0; s < 4; s++) {
    den += pl[(s * 16 + bh) * 1024 + qi];
    union { uint64_t q; uint16_t u[4]; } v;
    v.q = *(const uint64_t*)&po[(((size_t)(s * 16 + bh)) * 1024 + qi) * 128 + d0];
#pragma unroll
    for (int j = 0; j < 4; j++) acc[j] += bf2f(v.u[j]);
  }
  const float inv = 1.0f / den;
  union { uint64_t q; uint16_t u[4]; } o;
#pragma unroll
  for (int j = 0; j < 4; j++) o.u[j] = f2bf(acc[j] * inv);
  *(uint64_t*)&attb[((size_t)(b * 1024 + qi)) * 1024 + h * 128 + d0] = o.q;
}

// ---------------- launch ----------------
extern "C" void kernel_launch(void* const* d_in, const int* in_sizes, int n_in,
                              void* d_out, int out_size, void* d_ws, size_t ws_size,
                              hipStream_t stream) {
  (void)in_sizes; (void)n_in; (void)out_size; (void)ws_size;
  const float* x    = (const float*)d_in[0];
  const float* ctx  = (const float*)d_in[1];
  const float* sims = (const float*)d_in[2];
  const float* Wq   = (const float*)d_in[3];
  const float* Wkv  = (const float*)d_in[4];
  const float* beta = (const float*)d_in[5];
  const float* Wout = (const float*)d_in[6];
  const float* bout = (const float*)d_in[7];
  float* out = (float*)d_out;

  char* ws = (char*)d_ws;
  uint16_t* xb    = (uint16_t*)(ws + 0);           // 4 MB  (dead after fused GEMM)
  uint16_t* ctxb  = (uint16_t*)(ws + (4u << 20));  // 16 MB (dead after fused GEMM)
  uint16_t* wqt   = (uint16_t*)(ws + (20u << 20)); // 2 MB  (dead after fused GEMM)
  uint16_t* wkvt  = (uint16_t*)(ws + (22u << 20)); // 4 MB  (dead after fused GEMM)
  uint16_t* kb    = (uint16_t*)(ws + (32u << 20)); // 16 MB [2][8][4096][128]
  uint16_t* vtb   = (uint16_t*)(ws + (48u << 20)); // 16 MB [16][128][4096]
  float*    pl    = (float*)   (ws + (64u << 20)); // 256 KB used [64][1024]
  uint16_t* woutt = (uint16_t*)(ws + (68u << 20)); // 2 MB (live till end)
  uint16_t* qb    = (uint16_t*)(ws + (70u << 20)); // 4 MB (live till attn)
  uint16_t* attb  = (uint16_t*)(ws + (74u << 20)); // 4 MB
  // po (16 MB) reuses 0..16 MB: xb/ctxb dead by attention time
  uint16_t* po = (uint16_t*)(ws + 0);              // 16 MB [64][1024][128]

  const float LOG2E = 1.44269504f;
  const float qscale = 0.03125f * LOG2E;

  k_prep<<<14336, 256, 0, stream>>>(x, ctx, Wq, Wkv, Wout, xb, ctxb, wqt, wkvt, woutt, qscale);
  k_gemm_fused<<<1152, 256, 0, stream>>>(ctxb, wkvt, xb, wqt, kb, vtb, qb);
  k_attn<<<512, 256, 0, stream>>>(qb, kb, vtb, sims, beta, po, pl);
  k_merge<<<2048, 256, 0, stream>>>(po, pl, attb);
  k_gemm64<<<dim3(16, 32), 256, 0, stream>>>(attb, woutt, out, bout, 2048, 1024, 1024);
}